// Round 4
// baseline (129.595 us; speedup 1.0000x reference)
//
#include <hip/hip_runtime.h>

// HashGridPositionalEncoding4D — round 4.
//   B=8, N=131072, NUM_LEVELS=16, LEVEL_DIM=2, TABLE_SIZE=65536, D_MODEL=32
//
// Round-3 post-mortem: VGPR=24 proved the compiler re-fissioned the staged
// ILP=4 code into sequential chains (needs >=48 VGPR to hold 12 loads in
// flight). This round:
//   (a) sched_barrier(0) fences pin the stage structure: issue 4 coords ->
//       compute 8 hashes + issue 8 gathers + 4 x-loads -> consume. Gathers
//       from 4 independent points stay in flight together (true MLP).
//   (b) XCD level-partition: levels [0,8) handled by even blocks, [8,16) by
//       odd blocks. With XCD = blockIdx % 8 (round-robin), each XCD's gather
//       working set is 4 MB -> fits its private L2 (gathers were ~50% LLC
//       before). Perf-only assumption; correctness independent of mapping.
//
// Mapping: block = (pb, half). 256 threads = 64 local-points x 4 local-slots.
// slot = half*4 + ls covers levels 2*slot, 2*slot+1. Per point a block's 4
// slots cover one aligned 64B chunk of x/out (p*128 + half*64), so streams
// stay fully line-coalesced. ILP=4 points per thread (stride 64).

#define NPOINTS (8 * 131072)           // 1,048,576 points
#define ILP 4
#define TABLE_MASK 65535u

typedef float v4f __attribute__((ext_vector_type(4)));
typedef float v2f __attribute__((ext_vector_type(2)));

__global__ __launch_bounds__(256) void hashgrid4d_kernel(
    const float* __restrict__ x,
    const float* __restrict__ coords,
    const float* __restrict__ tables,
    const float* __restrict__ freq_bands,
    float* __restrict__ out)
{
    const int tid  = threadIdx.x;
    const int half = blockIdx.x & 1;       // level group: [8*half, 8*half+8)
    const int pb   = blockIdx.x >> 1;      // point-block (0..4095)
    const int ls   = tid & 3;              // local slot
    const int lp   = tid >> 2;             // local point (0..63)
    const int slot = half * 4 + ls;        // 0..7
    const int l0   = slot * 2;             // level of first gather

    const float f0 = freq_bands[l0];
    const float f1 = freq_bands[l0 + 1];

    // PRIMES rounded to float32 (identical to np.array(..., dtype=np.float32))
    const float P1 = 2654435761.0f;
    const float P2 = 805459861.0f;
    const float P3 = 3674653429.0f;

    const int p0 = pb * 256 + lp;          // point for k=0; +64 per k

    // ---- stage 1: issue all coords loads ----
    v4f c[ILP];
    #pragma unroll
    for (int k = 0; k < ILP; ++k) {
        c[k] = *reinterpret_cast<const v4f*>(coords + (size_t)(p0 + 64 * k) * 4);
    }
    __builtin_amdgcn_sched_barrier(0);

    // ---- stage 2: hash (VALU) + issue all 8 gathers ----
    v2f ft[ILP][2];
    #pragma unroll
    for (int k = 0; k < ILP; ++k) {
        const float c0 = fminf(fmaxf(c[k].x, 0.0f), 1.0f);
        const float c1 = fminf(fmaxf(c[k].y, 0.0f), 1.0f);
        const float c2 = fminf(fmaxf(c[k].z, 0.0f), 1.0f);
        const float c3 = fminf(fmaxf(c[k].w, 0.0f), 1.0f);
        #pragma unroll
        for (int j = 0; j < 2; ++j) {
            const float f = j ? f1 : f0;
            // v = (c*f)*P : two separate rn-multiplies, no FMA/reassoc (bit-
            // exact vs numpy). mod 2^32 + astype(uint32) of non-negative f32
            // == trunc to u64 then wrap to u32 (fmod is exact in IEEE).
            const float t0 = __fmul_rn(c0, f);
            const float t1 = __fmul_rn(c1, f);
            const float t2 = __fmul_rn(c2, f);
            const float t3 = __fmul_rn(c3, f);
            const unsigned int h0 = (unsigned int)(unsigned long long)t0;
            const unsigned int h1 = (unsigned int)(unsigned long long)__fmul_rn(t1, P1);
            const unsigned int h2 = (unsigned int)(unsigned long long)__fmul_rn(t2, P2);
            const unsigned int h3 = (unsigned int)(unsigned long long)__fmul_rn(t3, P3);
            const unsigned int idx = (h0 ^ h1 ^ h2 ^ h3) & TABLE_MASK;
            ft[k][j] = *reinterpret_cast<const v2f*>(
                tables + (((size_t)(l0 + j) << 16) + idx) * 2);
        }
    }

    // ---- stage 3: issue all x loads (non-temporal stream) ----
    v4f xv[ILP];
    #pragma unroll
    for (int k = 0; k < ILP; ++k) {
        const size_t off = (size_t)(p0 + 64 * k) * 32 + (size_t)slot * 4;
        xv[k] = __builtin_nontemporal_load(reinterpret_cast<const v4f*>(x + off));
    }
    __builtin_amdgcn_sched_barrier(0);

    // ---- stage 4: consume: add + non-temporal store ----
    #pragma unroll
    for (int k = 0; k < ILP; ++k) {
        const size_t off = (size_t)(p0 + 64 * k) * 32 + (size_t)slot * 4;
        v4f o;
        o.x = xv[k].x + ft[k][0].x;
        o.y = xv[k].y + ft[k][0].y;
        o.z = xv[k].z + ft[k][1].x;
        o.w = xv[k].w + ft[k][1].y;
        __builtin_nontemporal_store(o, reinterpret_cast<v4f*>(out + off));
    }
}

extern "C" void kernel_launch(void* const* d_in, const int* in_sizes, int n_in,
                              void* d_out, int out_size, void* d_ws, size_t ws_size,
                              hipStream_t stream) {
    const float* x          = (const float*)d_in[0];
    const float* coords     = (const float*)d_in[1];
    const float* tables     = (const float*)d_in[2];
    const float* freq_bands = (const float*)d_in[3];
    float* out              = (float*)d_out;

    // blocks: (NPOINTS / 256 points-per-block) x 2 level-halves
    const int grid = (NPOINTS / 256) * 2;   // 8192
    hashgrid4d_kernel<<<grid, 256, 0, stream>>>(x, coords, tables, freq_bands, out);
}